// Round 4
// baseline (230.364 us; speedup 1.0000x reference)
//
#include <hip/hip_runtime.h>
#include <cstdint>
#include <cstddef>

// ---------------- problem constants ----------------
#define BB 4
#define SS 2048
#define EE 512
#define HH 8
#define DD 64
#define MM (BB*SS)                       // 8192 token rows
#define BHSD ((size_t)BB*HH*SS*DD)       // 4194304 elements per q/k/v head tensor

static constexpr float SCALE_INV = 1.0f / 181.0f;   // SCALE = float(512 // 8**0.5) = 181.0
static constexpr float LN_EPS = 1e-5f;

typedef float  v4f  __attribute__((ext_vector_type(4)));
typedef __bf16 v8bf __attribute__((ext_vector_type(8)));
typedef __bf16 v4bf __attribute__((ext_vector_type(4)));

static __device__ __forceinline__ v4f mfma16(v8bf a, v8bf b, v4f c) {
  return __builtin_amdgcn_mfma_f32_16x16x32_bf16(a, b, c, 0, 0, 0);
}

// ---------------- workspace layout (bytes) ----------------
// Xb  bf16 [3][M][E]       : 25165824   (q,k,v inputs as bf16)
// Wb  bf16 [4][E][E]       :  2097152   (Wq,Wk,Wv,Wo as bf16)
// Xh  bf16 [3][B][H][S][D] : 25165824   (LN'd head-split q,k,v)
// AO  bf16 [M][E]          :  8388608   (attention output, merged heads)
// maskF f32 [3][M]         :    98304
static constexpr size_t oXb = 0;
static constexpr size_t oWb = oXb + (size_t)3*MM*EE*2;
static constexpr size_t oXh = oWb + (size_t)4*EE*EE*2;
static constexpr size_t oAO = oXh + (size_t)3*MM*EE*2;
static constexpr size_t oMk = oAO + (size_t)MM*EE*2;

// ================= mask canonicalization =================
// Bool masks may arrive as int32(0/1), float32(0.0/1.0), or 1-byte bools.
// Classify from the first 2048 u32 words (8 KB -- in-bounds for all three):
//   all words in {0,1}          -> int32
//   all words in {0,0x3F800000} -> float32
//   else                        -> byte bools
__global__ void mask_kernel(const void* qm, const void* km, const void* vm, float* maskF) {
  __shared__ int s_n01, s_nF;
  const int t = threadIdx.x;
  if (t == 0) { s_n01 = 0; s_nF = 0; }
  __syncthreads();
  int n01 = 0, nF = 0;
  const unsigned* wq = (const unsigned*)qm;
  for (int i = t; i < 2048; i += 256) {
    const unsigned u = wq[i];
    if (u != 0u && u != 1u) n01 = 1;
    if (u != 0u && u != 0x3F800000u) nF = 1;
  }
  if (n01) atomicOr(&s_n01, 1);
  if (nF)  atomicOr(&s_nF, 1);
  __syncthreads();
  const int mode = (!s_n01) ? 0 : (!s_nF) ? 1 : 2;   // 0=i32, 1=f32, 2=u8
  for (int m = 0; m < 3; ++m) {
    const void* p = (m == 0) ? qm : (m == 1) ? km : vm;
    for (int i = t; i < MM; i += 256) {
      int v;
      if (mode == 0)      v = (((const int*)p)[i] != 0);
      else if (mode == 1) v = (((const unsigned*)p)[i] != 0u);
      else                v = (((const unsigned char*)p)[i] != 0);
      maskF[m*MM + i] = v ? 1.0f : 0.0f;
    }
  }
}

// ================= fp32 -> bf16 convert =================
__global__ void convert_kernel(const float* q, const float* k, const float* v,
                               const float* Wq, const float* Wk, const float* Wv, const float* Wo,
                               __bf16* Xb, __bf16* Wb) {
  const long idx = (long)blockIdx.x * 256 + threadIdx.x;     // in float4 units
  const long NX4 = (long)3*MM*EE/4;   // 3145728
  const long NW4 = (long)4*EE*EE/4;   // 262144
  if (idx < NX4) {
    const long per = (long)MM*EE/4;
    const long mat = idx / per, off = idx % per;
    const float* src = (mat == 0) ? q : (mat == 1) ? k : v;
    v4f val = ((const v4f*)src)[off];
    v4bf o; o[0]=(__bf16)val[0]; o[1]=(__bf16)val[1]; o[2]=(__bf16)val[2]; o[3]=(__bf16)val[3];
    ((v4bf*)Xb)[idx] = o;
  } else if (idx < NX4 + NW4) {
    const long j = idx - NX4;
    const long per = (long)EE*EE/4;
    const long mat = j / per, off = j % per;
    const float* src = (mat == 0) ? Wq : (mat == 1) ? Wk : (mat == 2) ? Wv : Wo;
    v4f val = ((const v4f*)src)[off];
    v4bf o; o[0]=(__bf16)val[0]; o[1]=(__bf16)val[1]; o[2]=(__bf16)val[2]; o[3]=(__bf16)val[3];
    ((v4bf*)Wb)[j] = o;
  }
}

// ===== projection GEMM + bias + mask + per-head LayerNorm, fused =====
// Xh[mat] = LN_head((X @ W^T + b) * mask), head-split [B][H][S][D], bf16 out.
// 128x128 tile, BK=32, 4 waves (2x2), each wave 64x64 = 4x4 frags of 16x16x32.
// Each wave's 64 N-columns are 64-aligned => exactly one head's D range, so
// LN reduces across 4 regs + 16 lanes (shfl_xor 1,2,4,8), like the softmax.
__global__ __launch_bounds__(256) void gemm_proj_ln(const __bf16* Xb, const __bf16* Wb,
                                                    const float* bq, const float* bk, const float* bv,
                                                    const float* gq, const float* betaq,
                                                    const float* gk, const float* betak,
                                                    const float* gv, const float* betav,
                                                    const float* maskF, __bf16* Xh) {
  const int m0  = blockIdx.x * 128;
  const int n0  = blockIdx.y * 128;
  const int mat = blockIdx.z;
  const __bf16* A = Xb + (size_t)mat*MM*EE;
  const __bf16* W = Wb + (size_t)mat*EE*EE;
  const float* bias = (mat == 0) ? bq : (mat == 1) ? bk : bv;
  const float* gam  = (mat == 0) ? gq : (mat == 1) ? gk : gv;
  const float* bet  = (mat == 0) ? betaq : (mat == 1) ? betak : betav;

  __shared__ __bf16 As[128*32];   // [row][k], 64B rows, 4-slot XOR swizzle
  __shared__ __bf16 Bs[128*32];

  const int t = threadIdx.x;
  const int lane = t & 63, w = t >> 6;
  const int wm = w >> 1, wn = w & 1;
  const int l15 = lane & 15, lg = lane >> 4;

  v4f acc[4][4];
  const v4f zf = {0.f, 0.f, 0.f, 0.f};
#pragma unroll
  for (int i = 0; i < 4; ++i)
#pragma unroll
    for (int j = 0; j < 4; ++j) acc[i][j] = zf;

  const int sr  = t >> 1;          // staging row 0..127
  const int sc0 = (t & 1) * 2;     // staging chunk base (of 4 x 16B per row)

  for (int kt = 0; kt < EE; kt += 32) {
    const __bf16* ga = A + (size_t)(m0 + sr)*EE + kt + sc0*8;
    const __bf16* gb = W + (size_t)(n0 + sr)*EE + kt + sc0*8;
#pragma unroll
    for (int i = 0; i < 2; ++i) {
      const int c = sc0 + i;
      const int dst = sr*64 + ((c*16) ^ ((sr & 3) << 4));
      *(v8bf*)((char*)As + dst) = *(const v8bf*)((const char*)ga + i*16);
      *(v8bf*)((char*)Bs + dst) = *(const v8bf*)((const char*)gb + i*16);
    }
    __syncthreads();
    v8bf afr[4], bfr[4];
#pragma unroll
    for (int i = 0; i < 4; ++i) {
      const int ra = wm*64 + i*16 + l15;
      afr[i] = *(const v8bf*)((const char*)As + ra*64 + ((16*lg) ^ ((ra & 3) << 4)));
      const int rb = wn*64 + i*16 + l15;
      bfr[i] = *(const v8bf*)((const char*)Bs + rb*64 + ((16*lg) ^ ((rb & 3) << 4)));
    }
#pragma unroll
    for (int i = 0; i < 4; ++i)
#pragma unroll
      for (int j = 0; j < 4; ++j)
        acc[i][j] = mfma16(afr[i], bfr[j], acc[i][j]);
    __syncthreads();
  }

  // ---- fused epilogue: bias, mask, per-head LN, bf16 store ----
  const int nbase = n0 + wn*64;          // 64-aligned => one head
  const int h = nbase >> 6;
  float bsv[4], gmv[4], btv[4];
#pragma unroll
  for (int j = 0; j < 4; ++j) {
    const int d = j*16 + l15;
    bsv[j] = bias[nbase + d];
    gmv[j] = gam[d];
    btv[j] = bet[d];
  }
#pragma unroll
  for (int i = 0; i < 4; ++i)
#pragma unroll
    for (int rr = 0; rr < 4; ++rr) {
      const int row = m0 + wm*64 + i*16 + 4*lg + rr;
      const float mv = maskF[mat*MM + row];
      float x[4];
      float s = 0.f, s2 = 0.f;
#pragma unroll
      for (int j = 0; j < 4; ++j) {
        x[j] = (acc[i][j][rr] + bsv[j]) * mv;
        s += x[j]; s2 += x[j]*x[j];
      }
      s  += __shfl_xor(s, 1, 64);  s  += __shfl_xor(s, 2, 64);
      s  += __shfl_xor(s, 4, 64);  s  += __shfl_xor(s, 8, 64);
      s2 += __shfl_xor(s2, 1, 64); s2 += __shfl_xor(s2, 2, 64);
      s2 += __shfl_xor(s2, 4, 64); s2 += __shfl_xor(s2, 8, 64);
      const float mu  = s * (1.0f/64.0f);
      const float var = s2 * (1.0f/64.0f) - mu*mu;
      const float rstd = rsqrtf(var + LN_EPS);
      const int bidx = row >> 11, sI = row & 2047;
      const size_t base = (size_t)mat*BHSD + (((size_t)bidx*HH + h)*SS + sI)*DD;
#pragma unroll
      for (int j = 0; j < 4; ++j)
        Xh[base + j*16 + l15] = (__bf16)((x[j] - mu)*rstd*gmv[j] + btv[j]);
    }
}

// ================= flash attention =================
// grid (16 q-tiles, H, B); block = 4 waves; wave handles 32 q rows; KVBLK=64.
__global__ __launch_bounds__(256) void attn_kernel(const __bf16* Xh, const float* maskF, __bf16* AO) {
  const int qb = blockIdx.x, h = blockIdx.y, b = blockIdx.z;
  const int t = threadIdx.x, lane = t & 63, w = t >> 6;
  const int l15 = lane & 15, lg = lane >> 4;

  const size_t headoff = (((size_t)b*HH + h)*SS)*DD;
  const __bf16* Qg = Xh + headoff;
  const __bf16* Kg = Xh + BHSD   + headoff;
  const __bf16* Vg = Xh + 2*BHSD + headoff;
  const float* qmF = maskF + (size_t)b*SS;           // query mask region [0]
  const float* kmF = maskF + MM + (size_t)b*SS;      // key mask region [1]

  __shared__ __bf16 Ks[64*64];      // [key][d], 128B rows, 8-slot XOR swizzle
  __shared__ __bf16 Vt[64*64];      // [d][key], 128B rows, 8-slot XOR swizzle
  __shared__ __bf16 Ps[4][32*64];   // per-wave P [qrow][key], swizzled

  const int q0 = qb*128 + w*32;

  v8bf qf[2][2];
#pragma unroll
  for (int m = 0; m < 2; ++m)
#pragma unroll
    for (int kd = 0; kd < 2; ++kd)
      qf[m][kd] = *(const v8bf*)(Qg + (size_t)(q0 + m*16 + l15)*DD + kd*32 + lg*8);

  v4f O[2][4];
  float mrun[2][4], lrun[2][4];
  const v4f zf = {0.f,0.f,0.f,0.f};
#pragma unroll
  for (int m = 0; m < 2; ++m) {
#pragma unroll
    for (int df = 0; df < 4; ++df) O[m][df] = zf;
#pragma unroll
    for (int rr = 0; rr < 4; ++rr) { mrun[m][rr] = -INFINITY; lrun[m][rr] = 0.f; }
  }

  for (int kt0 = 0; kt0 < SS; kt0 += 64) {
    __syncthreads();   // previous iteration's LDS reads complete
    {
      // stage K tile (swizzled rows)
      const int r = t >> 2;
      const __bf16* gk_ = Kg + (size_t)(kt0 + r)*DD;
#pragma unroll
      for (int i = 0; i < 2; ++i) {
        const int c = (t & 3)*2 + i;
        *(v8bf*)((char*)Ks + r*128 + ((c*16) ^ ((r & 7) << 4))) = *(const v8bf*)(gk_ + c*8);
      }
      // stage V transposed: thread owns key kk, d-range [d0, d0+16)
      const int kk = t & 63;
      const int d0 = (t >> 6) * 16;
      const __bf16* gv_ = Vg + (size_t)(kt0 + kk)*DD + d0;
      v8bf v0 = *(const v8bf*)(gv_);
      v8bf v1 = *(const v8bf*)(gv_ + 8);
#pragma unroll
      for (int j = 0; j < 8; ++j) {
        const int d  = d0 + j, d2 = d0 + 8 + j;
        *(__bf16*)((char*)Vt + d *128 + ((kk*2) ^ ((d  & 7) << 4))) = v0[j];
        *(__bf16*)((char*)Vt + d2*128 + ((kk*2) ^ ((d2 & 7) << 4))) = v1[j];
      }
    }
    __syncthreads();

    // ---- QK^T ----
    v4f sacc[2][4];
#pragma unroll
    for (int m = 0; m < 2; ++m)
#pragma unroll
      for (int f = 0; f < 4; ++f) sacc[m][f] = zf;
#pragma unroll
    for (int kd = 0; kd < 2; ++kd) {
      v8bf kf[4];
#pragma unroll
      for (int f = 0; f < 4; ++f) {
        const int r = f*16 + l15;
        kf[f] = *(const v8bf*)((const char*)Ks + r*128 + ((kd*64 + 16*lg) ^ ((r & 7) << 4)));
      }
#pragma unroll
      for (int m = 0; m < 2; ++m)
#pragma unroll
        for (int f = 0; f < 4; ++f)
          sacc[m][f] = mfma16(qf[m][kd], kf[f], sacc[m][f]);
    }

    // ---- online softmax (fp32) ----
    float kmv[4];
#pragma unroll
    for (int f = 0; f < 4; ++f) kmv[f] = kmF[kt0 + f*16 + l15];

#pragma unroll
    for (int m = 0; m < 2; ++m) {
      float mt[4] = {-3e38f, -3e38f, -3e38f, -3e38f};
#pragma unroll
      for (int f = 0; f < 4; ++f)
#pragma unroll
        for (int rr = 0; rr < 4; ++rr) {
          const float sv = (kmv[f] > 0.5f) ? sacc[m][f][rr]*SCALE_INV : -1e9f;
          sacc[m][f][rr] = sv;
          mt[rr] = fmaxf(mt[rr], sv);
        }
#pragma unroll
      for (int rr = 0; rr < 4; ++rr) {
        float v = mt[rr];
        v = fmaxf(v, __shfl_xor(v, 1, 64));
        v = fmaxf(v, __shfl_xor(v, 2, 64));
        v = fmaxf(v, __shfl_xor(v, 4, 64));
        v = fmaxf(v, __shfl_xor(v, 8, 64));
        const float mnew = fmaxf(mrun[m][rr], v);
        const float corr = __expf(mrun[m][rr] - mnew);
        mrun[m][rr] = mnew;
#pragma unroll
        for (int df = 0; df < 4; ++df) O[m][df][rr] *= corr;
        float lt = 0.f;
#pragma unroll
        for (int f = 0; f < 4; ++f) {
          const float p = __expf(sacc[m][f][rr] - mnew);
          sacc[m][f][rr] = p;
          lt += p;
        }
        lt += __shfl_xor(lt, 1, 64);
        lt += __shfl_xor(lt, 2, 64);
        lt += __shfl_xor(lt, 4, 64);
        lt += __shfl_xor(lt, 8, 64);
        lrun[m][rr] = lrun[m][rr]*corr + lt;
      }
      // write P tile (bf16) to this wave's swizzled LDS buffer
#pragma unroll
      for (int f = 0; f < 4; ++f)
#pragma unroll
        for (int rr = 0; rr < 4; ++rr) {
          const int prow = m*16 + 4*lg + rr;
          const int pcol = f*16 + l15;
          *(__bf16*)((char*)&Ps[w][0] + prow*128 + ((pcol*2) ^ ((prow & 7) << 4))) = (__bf16)sacc[m][f][rr];
        }
    }
    __syncthreads();

    // ---- P @ V ----
#pragma unroll
    for (int ks = 0; ks < 2; ++ks) {
      v8bf pf[2], vf[4];
#pragma unroll
      for (int m = 0; m < 2; ++m) {
        const int r = m*16 + l15;
        pf[m] = *(const v8bf*)((const char*)&Ps[w][0] + r*128 + ((ks*64 + 16*lg) ^ ((r & 7) << 4)));
      }
#pragma unroll
      for (int df = 0; df < 4; ++df) {
        const int r = df*16 + l15;
        vf[df] = *(const v8bf*)((const char*)Vt + r*128 + ((ks*64 + 16*lg) ^ ((r & 7) << 4)));
      }
#pragma unroll
      for (int m = 0; m < 2; ++m)
#pragma unroll
        for (int df = 0; df < 4; ++df)
          O[m][df] = mfma16(pf[m], vf[df], O[m][df]);
    }
  }

  // epilogue: normalize, query-mask, store bf16 AO[b*S+q][E]
#pragma unroll
  for (int m = 0; m < 2; ++m)
#pragma unroll
    for (int rr = 0; rr < 4; ++rr) {
      const int qrow = q0 + m*16 + 4*lg + rr;
      const float scl = qmF[qrow] / lrun[m][rr];
#pragma unroll
      for (int df = 0; df < 4; ++df)
        AO[(size_t)(b*SS + qrow)*EE + h*DD + df*16 + l15] = (__bf16)(O[m][df][rr] * scl);
    }
}

// ================= output GEMM: out = (AO @ Wo^T + bo) * qmask =================
__global__ __launch_bounds__(256) void gemm_out(const __bf16* AO, const __bf16* Wb,
                                                const float* bo, const float* maskF, float* out) {
  const int m0 = blockIdx.x * 128;
  const int n0 = blockIdx.y * 128;
  const __bf16* A = AO;
  const __bf16* W = Wb + (size_t)3*EE*EE;   // Wo

  __shared__ __bf16 As[128*32];
  __shared__ __bf16 Bs[128*32];

  const int t = threadIdx.x;
  const int lane = t & 63, w = t >> 6;
  const int wm = w >> 1, wn = w & 1;
  const int l15 = lane & 15, lg = lane >> 4;

  v4f acc[4][4];
  const v4f zf = {0.f,0.f,0.f,0.f};
#pragma unroll
  for (int i = 0; i < 4; ++i)
#pragma unroll
    for (int j = 0; j < 4; ++j) acc[i][j] = zf;

  const int sr  = t >> 1;
  const int sc0 = (t & 1) * 2;

  for (int kt = 0; kt < EE; kt += 32) {
    const __bf16* ga = A + (size_t)(m0 + sr)*EE + kt + sc0*8;
    const __bf16* gb = W + (size_t)(n0 + sr)*EE + kt + sc0*8;
#pragma unroll
    for (int i = 0; i < 2; ++i) {
      const int c = sc0 + i;
      const int dst = sr*64 + ((c*16) ^ ((sr & 3) << 4));
      *(v8bf*)((char*)As + dst) = *(const v8bf*)((const char*)ga + i*16);
      *(v8bf*)((char*)Bs + dst) = *(const v8bf*)((const char*)gb + i*16);
    }
    __syncthreads();
    v8bf afr[4], bfr[4];
#pragma unroll
    for (int i = 0; i < 4; ++i) {
      const int ra = wm*64 + i*16 + l15;
      afr[i] = *(const v8bf*)((const char*)As + ra*64 + ((16*lg) ^ ((ra & 3) << 4)));
      const int rb = wn*64 + i*16 + l15;
      bfr[i] = *(const v8bf*)((const char*)Bs + rb*64 + ((16*lg) ^ ((rb & 3) << 4)));
    }
#pragma unroll
    for (int i = 0; i < 4; ++i)
#pragma unroll
      for (int j = 0; j < 4; ++j)
        acc[i][j] = mfma16(afr[i], bfr[j], acc[i][j]);
    __syncthreads();
  }

  float bsv[4]; int ncol[4];
#pragma unroll
  for (int j = 0; j < 4; ++j) {
    ncol[j] = n0 + wn*64 + j*16 + l15;
    bsv[j] = bo[ncol[j]];
  }
#pragma unroll
  for (int i = 0; i < 4; ++i)
#pragma unroll
    for (int rr = 0; rr < 4; ++rr) {
      const int row = m0 + wm*64 + i*16 + 4*lg + rr;
      const float mv = maskF[row];   // query mask
#pragma unroll
      for (int j = 0; j < 4; ++j)
        out[(size_t)row*EE + ncol[j]] = (acc[i][j][rr] + bsv[j]) * mv;
    }
}

// ================= launcher =================
extern "C" void kernel_launch(void* const* d_in, const int* in_sizes, int n_in,
                              void* d_out, int out_size, void* d_ws, size_t ws_size,
                              hipStream_t stream) {
  const float* q  = (const float*)d_in[0];
  const float* k  = (const float*)d_in[1];
  const float* v  = (const float*)d_in[2];
  const float* Wq = (const float*)d_in[3];
  const float* bq = (const float*)d_in[4];
  const float* Wk = (const float*)d_in[5];
  const float* bk = (const float*)d_in[6];
  const float* Wv = (const float*)d_in[7];
  const float* bv = (const float*)d_in[8];
  const float* Wo = (const float*)d_in[9];
  const float* bo = (const float*)d_in[10];
  const float* gq = (const float*)d_in[11];
  const float* betaq = (const float*)d_in[12];
  const float* gk = (const float*)d_in[13];
  const float* betak = (const float*)d_in[14];
  const float* gv = (const float*)d_in[15];
  const float* betav = (const float*)d_in[16];

  char* ws = (char*)d_ws;
  __bf16* Xb = (__bf16*)(ws + oXb);
  __bf16* Wb = (__bf16*)(ws + oWb);
  __bf16* Xh = (__bf16*)(ws + oXh);
  __bf16* AO = (__bf16*)(ws + oAO);
  float*  maskF = (float*)(ws + oMk);

  mask_kernel<<<dim3(1), dim3(256), 0, stream>>>(d_in[17], d_in[18], d_in[19], maskF);
  convert_kernel<<<dim3(13312), dim3(256), 0, stream>>>(q, k, v, Wq, Wk, Wv, Wo, Xb, Wb);
  gemm_proj_ln<<<dim3(64, 4, 3), dim3(256), 0, stream>>>(Xb, Wb, bq, bk, bv,
                                                         gq, betaq, gk, betak, gv, betav,
                                                         maskF, Xh);
  attn_kernel<<<dim3(16, 8, 4), dim3(256), 0, stream>>>(Xh, maskF, AO);
  gemm_out<<<dim3(64, 4, 1), dim3(256), 0, stream>>>(AO, Wb, bo, maskF, (float*)d_out);
}